// Round 1
// baseline (619.809 us; speedup 1.0000x reference)
//
#include <hip/hip_runtime.h>
#include <math.h>

constexpr int D  = 256;   // d_model
constexpr int NP = 32;    // patterns
constexpr int BM = 64;    // rows per block
constexpr int BK = 32;    // k-chunk

// ---------- helpers ----------

__device__ __forceinline__ void async16(float* lds, const float* g) {
    // direct global->LDS, 16B per lane (lds dest must be linear in lane)
    __builtin_amdgcn_global_load_lds(
        (const __attribute__((address_space(1))) void*)g,
        (__attribute__((address_space(3))) void*)lds, 16, 0, 0);
}

__device__ __forceinline__ float rsum32(float v) {
#pragma unroll
    for (int m = 16; m; m >>= 1) v += __shfl_xor(v, m, 64);
    return v;
}

// ---------- prep: W transpose, pattern l2-normalize, hist zero ----------

__global__ __launch_bounds__(256) void vq_prep(
    const float* __restrict__ Wq, const float* __restrict__ pat,
    float* __restrict__ Wt, float* __restrict__ Pn,
    float* __restrict__ nrmv, float* __restrict__ hist)
{
    const int bid = blockIdx.x, tid = threadIdx.x;
    if (bid < 256) {
        // Wt[k][e] = Wq[e][k]
        float v = Wq[bid * 256 + tid];
        Wt[tid * 256 + bid] = v;
    } else if (bid < 256 + NP) {
        const int p = bid - 256;
        float v = pat[p * 256 + tid];
        float ss = v * v;
#pragma unroll
        for (int m = 32; m; m >>= 1) ss += __shfl_xor(ss, m, 64);
        __shared__ float ws[4];
        if ((tid & 63) == 0) ws[tid >> 6] = ss;
        __syncthreads();
        float tot = ws[0] + ws[1] + ws[2] + ws[3];
        float n = fmaxf(sqrtf(tot), 1e-12f);
        Pn[p * 256 + tid] = v / n;
        if (tid == 0) nrmv[p] = n;
    } else {
        if (tid < NP) hist[tid] = 0.f;
    }
}

// ---------- main fused kernel ----------

__global__ __launch_bounds__(256, 3) void vq_main(
    const float* __restrict__ x, const float* __restrict__ Wt,
    const float* __restrict__ bq, const float* __restrict__ lnw,
    const float* __restrict__ lnb, const float* __restrict__ Pn,
    const float* __restrict__ nrmv, const int* __restrict__ epoch,
    const int* __restrict__ tot_ep, float* __restrict__ out,
    float* __restrict__ g_hist, int rows)
{
    __shared__ float As[BM * BK];   // A tile [64 rows][32 k]; reused as hist later
    __shared__ float SB[BK * D];    // W chunk [32 k][256 e]; reused for Pn [32][256]

    const int tid = threadIdx.x;
    const int tx = tid & 31, ty = tid >> 5;
    const int c0 = tx * 4, c1 = 128 + tx * 4;
    const long row0 = (long)blockIdx.x * BM;

    float acc[8][8];
#pragma unroll
    for (int i = 0; i < 8; ++i)
#pragma unroll
        for (int j = 0; j < 8; ++j) acc[i][j] = 0.f;

    // ---- GEMM: h = x @ Wq^T  (acc[rr][cc], rows ty*8+rr, cols c0..c0+3,c1..c1+3)
    for (int kc = 0; kc < D / BK; ++kc) {
        __syncthreads();
#pragma unroll
        for (int i = 0; i < 2; ++i) {           // A: 64x32 f32 = 512 x 16B
            int ff = i * 256 + tid;
            int r = ff >> 3, j = ff & 7;
            async16(&As[ff * 4], x + (row0 + r) * D + kc * BK + j * 4);
        }
        const float* wsrc = Wt + kc * BK * D;   // contiguous 32KB
#pragma unroll
        for (int i = 0; i < 8; ++i) {
            int ff = i * 256 + tid;
            async16(&SB[ff * 4], wsrc + ff * 4);
        }
        __syncthreads();                        // drains vmcnt -> staging complete
#pragma unroll
        for (int k = 0; k < BK; ++k) {
            float4 w0 = *(const float4*)&SB[k * D + c0];
            float4 w1 = *(const float4*)&SB[k * D + c1];
            float a[8];
#pragma unroll
            for (int rr = 0; rr < 8; ++rr) a[rr] = As[(ty * 8 + rr) * BK + k];
#pragma unroll
            for (int rr = 0; rr < 8; ++rr) {
                acc[rr][0] = fmaf(a[rr], w0.x, acc[rr][0]);
                acc[rr][1] = fmaf(a[rr], w0.y, acc[rr][1]);
                acc[rr][2] = fmaf(a[rr], w0.z, acc[rr][2]);
                acc[rr][3] = fmaf(a[rr], w0.w, acc[rr][3]);
                acc[rr][4] = fmaf(a[rr], w1.x, acc[rr][4]);
                acc[rr][5] = fmaf(a[rr], w1.y, acc[rr][5]);
                acc[rr][6] = fmaf(a[rr], w1.z, acc[rr][6]);
                acc[rr][7] = fmaf(a[rr], w1.w, acc[rr][7]);
            }
        }
    }

    // per-column constants
    float4 bq0 = *(const float4*)&bq[c0],  bq1 = *(const float4*)&bq[c1];
    float4 lw0 = *(const float4*)&lnw[c0], lw1 = *(const float4*)&lnw[c1];
    float4 lb0 = *(const float4*)&lnb[c0], lb1 = *(const float4*)&lnb[c1];
    float bqv[8] = {bq0.x, bq0.y, bq0.z, bq0.w, bq1.x, bq1.y, bq1.z, bq1.w};
    float lwv[8] = {lw0.x, lw0.y, lw0.z, lw0.w, lw1.x, lw1.y, lw1.z, lw1.w};
    float lbv[8] = {lb0.x, lb0.y, lb0.z, lb0.w, lb1.x, lb1.y, lb1.z, lb1.w};

    // ---- stage normalized patterns into SB; zero LDS hist (reuse As)
    __syncthreads();
#pragma unroll
    for (int i = 0; i < 8; ++i) {
        int ff = i * 256 + tid;
        async16(&SB[ff * 4], Pn + ff * 4);
    }
    if (tid < NP) As[tid] = 0.f;
    __syncthreads();

    float temp;
    {
        float pe = (float)epoch[0] / (float)tot_ep[0];
        temp = fmaxf(0.5f, 1.0f - 0.5f * pe);
    }
    const float nrm_p = nrmv[tx];   // raw-pattern norm for p = tx

    // ---- bias + LayerNorm + L2 normalize (row lives across 32 lanes, 8 cols each)
#pragma unroll
    for (int rr = 0; rr < 8; ++rr) {
        float* h = acc[rr];
        float s = 0.f;
#pragma unroll
        for (int i = 0; i < 8; ++i) { h[i] += bqv[i]; s += h[i]; }
        s = rsum32(s);
        float mu = s * 0.00390625f;            // /256
        float ss = 0.f;
#pragma unroll
        for (int i = 0; i < 8; ++i) { float d = h[i] - mu; h[i] = d; ss += d * d; }
        ss = rsum32(ss);
        float rstd = rsqrtf(ss * 0.00390625f + 1e-5f);
        float s2 = 0.f;
#pragma unroll
        for (int i = 0; i < 8; ++i) { float v = h[i] * rstd * lwv[i] + lbv[i]; h[i] = v; s2 += v * v; }
        s2 = rsum32(s2);
        float dn = fmaxf(sqrtf(s2), 1e-12f);
        float inv = 1.0f / dn;
#pragma unroll
        for (int i = 0; i < 8; ++i) h[i] *= inv;
    }

    // output section bases (floats)
    const long ob_a = (long)rows * D;
    const long ob_l = ob_a + (long)rows * NP;
    const long ob_h = ob_l + (long)rows * NP;

    // ---- logits / softmax / argmax per row
    float sfr[8];
#pragma unroll
    for (int rr = 0; rr < 8; ++rr) {
        float pa[32];
        const float* h = acc[rr];
#pragma unroll
        for (int p = 0; p < NP; ++p) {
            float4 v0 = *(const float4*)&SB[p * D + c0];
            float4 v1 = *(const float4*)&SB[p * D + c1];
            pa[p] = h[0] * v0.x + h[1] * v0.y + h[2] * v0.z + h[3] * v0.w
                  + h[4] * v1.x + h[5] * v1.y + h[6] * v1.z + h[7] * v1.w;
        }
        // butterfly transpose-reduce: lane tx ends with full logit for p = tx
        int L = 32;
#pragma unroll
        for (int m = 16; m; m >>= 1) {
            int half = L >> 1;
#pragma unroll
            for (int j = 0; j < 16; ++j) {
                if (j < half) {
                    float send = (tx & m) ? pa[j] : pa[j + half];
                    float recv = __shfl_xor(send, m, 64);
                    float keep = (tx & m) ? pa[j + half] : pa[j];
                    pa[j] = keep + recv;
                }
            }
            L = half;
        }
        float lg = pa[0] / temp;
        // softmax over 32 lanes
        float mx = lg;
#pragma unroll
        for (int m = 16; m; m >>= 1) mx = fmaxf(mx, __shfl_xor(mx, m, 64));
        float e = expf(lg - mx);
        float se = rsum32(e);
        float soft = e / se;
        sfr[rr] = soft;
        // argmax, first-index tie-break (matches jnp.argmax)
        float bv = lg; int bi = tx;
#pragma unroll
        for (int m = 16; m; m >>= 1) {
            float ov = __shfl_xor(bv, m, 64);
            int   oi = __shfl_xor(bi, m, 64);
            if (ov > bv || (ov == bv && oi < bi)) { bv = ov; bi = oi; }
        }
        long grow = row0 + ty * 8 + rr;
        out[ob_a + grow * NP + tx] = soft;
        out[ob_l + grow * NP + tx] = lg;
        if (tx == 0) {
            out[ob_h + grow] = (float)bi;
            atomicAdd(&As[bi], 1.0f);          // LDS histogram
        }
    }

    // ---- pattern_emb = soft @ patterns  (raw patterns = Pn * nrm, fold norm into soft)
    float s2r[8];
#pragma unroll
    for (int rr = 0; rr < 8; ++rr) s2r[rr] = sfr[rr] * nrm_p;
#pragma unroll
    for (int i = 0; i < 8; ++i)
#pragma unroll
        for (int j = 0; j < 8; ++j) acc[i][j] = 0.f;

#pragma unroll
    for (int p = 0; p < NP; ++p) {
        float4 v0 = *(const float4*)&SB[p * D + c0];
        float4 v1 = *(const float4*)&SB[p * D + c1];
#pragma unroll
        for (int rr = 0; rr < 8; ++rr) {
            float sp = __shfl(s2r[rr], p, 32);
            acc[rr][0] = fmaf(sp, v0.x, acc[rr][0]);
            acc[rr][1] = fmaf(sp, v0.y, acc[rr][1]);
            acc[rr][2] = fmaf(sp, v0.z, acc[rr][2]);
            acc[rr][3] = fmaf(sp, v0.w, acc[rr][3]);
            acc[rr][4] = fmaf(sp, v1.x, acc[rr][4]);
            acc[rr][5] = fmaf(sp, v1.y, acc[rr][5]);
            acc[rr][6] = fmaf(sp, v1.z, acc[rr][6]);
            acc[rr][7] = fmaf(sp, v1.w, acc[rr][7]);
        }
    }
#pragma unroll
    for (int rr = 0; rr < 8; ++rr) {
        long grow = row0 + ty * 8 + rr;
        float4 o0 = {acc[rr][0], acc[rr][1], acc[rr][2], acc[rr][3]};
        float4 o1 = {acc[rr][4], acc[rr][5], acc[rr][6], acc[rr][7]};
        *(float4*)&out[grow * D + c0] = o0;
        *(float4*)&out[grow * D + c1] = o1;
    }

    __syncthreads();
    if (tid < NP) atomicAdd(&g_hist[tid], As[tid]);
}

// ---------- tail: usage + EMA outputs ----------

__global__ __launch_bounds__(256) void vq_tail(
    const float* __restrict__ g_hist, const float* __restrict__ usage,
    const float* __restrict__ ema, const float* __restrict__ pat,
    float* __restrict__ out, int rows)
{
    const int tid = threadIdx.x;
    const long base_u = (long)rows * D + 2L * rows * NP + rows;
    const long base_e = base_u + NP;
    if (tid < 64) {
        float h = (tid < NP) ? g_hist[tid] : 0.f;
        float s = h;
#pragma unroll
        for (int m = 16; m; m >>= 1) s += __shfl_xor(s, m, 64);
        if (tid < NP)
            out[base_u + tid] = 0.9f * usage[tid] + 0.1f * (h / (s + 1e-8f));
    }
    for (int i = tid; i < NP * D; i += 256)
        out[base_e + i] = 0.99f * ema[i] + 0.01f * pat[i];
}

// ---------- launcher ----------

extern "C" void kernel_launch(void* const* d_in, const int* in_sizes, int n_in,
                              void* d_out, int out_size, void* d_ws, size_t ws_size,
                              hipStream_t stream) {
    const float* x     = (const float*)d_in[0];
    const float* Wq    = (const float*)d_in[1];
    const float* bq    = (const float*)d_in[2];
    const float* lnw   = (const float*)d_in[3];
    const float* lnb   = (const float*)d_in[4];
    const float* pat   = (const float*)d_in[5];
    const float* usage = (const float*)d_in[6];
    const float* ema   = (const float*)d_in[7];
    const int*   ep    = (const int*)d_in[8];
    const int*   te    = (const int*)d_in[9];
    float* out = (float*)d_out;
    const int rows = in_sizes[0] / D;          // B*T = 131072

    // ws layout: hist(128B) | pad | Wt(256KB) | Pn(32KB) | nrm(128B)
    float* hist = (float*)d_ws;
    float* Wt   = (float*)((char*)d_ws + 1024);
    float* Pn   = (float*)((char*)d_ws + 1024 + 256 * 1024);
    float* nv   = (float*)((char*)d_ws + 1024 + 256 * 1024 + 32 * 1024);

    vq_prep<<<256 + NP + 1, 256, 0, stream>>>(Wq, pat, Wt, Pn, nv, hist);
    vq_main<<<rows / BM, 256, 0, stream>>>(x, Wt, bq, lnw, lnb, Pn, nv,
                                           ep, te, out, hist, rows);
    vq_tail<<<1, 256, 0, stream>>>(hist, usage, ema, pat, out, rows);
}